// Round 1
// 466.771 us; speedup vs baseline: 1.0822x; 1.0822x over previous
//
#include <hip/hip_runtime.h>
#include <hip/hip_bf16.h>

// Problem: B=4, T=1024, C=1024, H=16, D=64. ALiBi encoder attention.
// Outputs: y [B,T,C] (4,194,304 fp32) then attn [B,H,T,T] (67,108,864 fp32).

typedef _Float16 half8 __attribute__((ext_vector_type(8)));
typedef _Float16 half4 __attribute__((ext_vector_type(4)));
typedef float f32x4 __attribute__((ext_vector_type(4)));

#define MFMA16(a, b, c) __builtin_amdgcn_mfma_f32_16x16x32_f16((a), (b), (c), 0, 0, 0)

// ---------------------------------------------------------------- convert ---
// Single launch converting x + all 4 weight matrices (saves 4 launch slots).
__global__ __launch_bounds__(256) void cvt_all(
    const float* __restrict__ x, const float* __restrict__ wq,
    const float* __restrict__ wk, const float* __restrict__ wv,
    const float* __restrict__ wp, _Float16* __restrict__ x16,
    _Float16* __restrict__ wq16, _Float16* __restrict__ wk16,
    _Float16* __restrict__ wv16, _Float16* __restrict__ wp16) {
  int i = blockIdx.x * 256 + threadIdx.x;  // float4 index; total 2,097,152
  const float* src;
  _Float16* dst;
  int off;
  if (i < 1048576) {
    src = x; dst = x16; off = i;
  } else {
    int j = i - 1048576;
    int sel = j >> 18;          // 262144 float4 per weight
    off = j & 262143;
    src = (sel == 0) ? wq : (sel == 1) ? wk : (sel == 2) ? wv : wp;
    dst = (sel == 0) ? wq16 : (sel == 1) ? wk16 : (sel == 2) ? wv16 : wp16;
  }
  float4 v = ((const float4*)src)[off];
  half4 o = {(_Float16)v.x, (_Float16)v.y, (_Float16)v.z, (_Float16)v.w};
  *(half4*)&dst[(size_t)off * 4] = o;
}

// ------------------------------------------------------------- gemm core ----
// m97-class structure: 128x128 tile, BK=64, 256 threads (4 waves in 2x2),
// 16x16x32 f16 MFMA, 16B global_load_lds staging, 2 barriers per 64-K step.
// XOR-8 swizzle on 16B k-chunks: rows stride 128B in LDS, chunk' = chunk ^
// (row&7) spreads the 16 lm-lanes across all 8 chunk slots -> 2-way residual
// bank aliasing (free on CDNA4).
__device__ __forceinline__ void stage_tile(const _Float16* gbase, _Float16* lds, int tid) {
#pragma unroll
  for (int i = 0; i < 4; ++i) {
    int cid = i * 256 + tid;            // 0..1023 16B chunks (128 rows x 8)
    int row = cid >> 3, jl = cid & 7;
    int jg = jl ^ (row & 7);            // global chunk placed at lds chunk jl
    const _Float16* gp = gbase + (size_t)row * 1024 + jg * 8;
    _Float16* lp = lds + (size_t)cid * 8;  // linear: uniform base + lane*16B
    __builtin_amdgcn_global_load_lds(
        (const __attribute__((address_space(1))) unsigned int*)gp,
        (__attribute__((address_space(3))) unsigned int*)lp, 16, 0, 0);
  }
}

__device__ __forceinline__ void gemm_core(const _Float16* __restrict__ A,
                                          const _Float16* __restrict__ B,
                                          int m0, int n0, int tid,
                                          f32x4 (&acc)[4][4]) {
  __shared__ _Float16 As[128 * 64];
  __shared__ _Float16 Bs[128 * 64];
  const int wave = tid >> 6, lane = tid & 63;
  const int wr = wave >> 1, wc = wave & 1;
  const int lg = lane >> 4, lm = lane & 15;

  f32x4 z4 = {0.f, 0.f, 0.f, 0.f};
#pragma unroll
  for (int mt = 0; mt < 4; ++mt)
#pragma unroll
    for (int nt = 0; nt < 4; ++nt) acc[mt][nt] = z4;

  for (int kb = 0; kb < 16; ++kb) {
    stage_tile(A + (size_t)m0 * 1024 + kb * 64, As, tid);
    stage_tile(B + (size_t)n0 * 1024 + kb * 64, Bs, tid);
    __syncthreads();
#pragma unroll
    for (int h = 0; h < 2; ++h) {       // two K=32 halves of the 64-K tile
      half8 af[4], bf[4];
#pragma unroll
      for (int mt = 0; mt < 4; ++mt) {
        int row = wr * 64 + mt * 16 + lm;
        int ch = (lg + h * 4) ^ (row & 7);
        af[mt] = *(half8*)&As[row * 64 + ch * 8];
      }
#pragma unroll
      for (int nt = 0; nt < 4; ++nt) {
        int row = wc * 64 + nt * 16 + lm;
        int ch = (lg + h * 4) ^ (row & 7);
        bf[nt] = *(half8*)&Bs[row * 64 + ch * 8];
      }
#pragma unroll
      for (int mt = 0; mt < 4; ++mt)
#pragma unroll
        for (int nt = 0; nt < 4; ++nt)
          acc[mt][nt] = MFMA16(af[mt], bf[nt], acc[mt][nt]);
    }
    __syncthreads();
  }
}

// ------------------------------------------------------------- QKV GEMM -----
// z=0: Q = 0.125 * x@Wq^T -> [B,H,T,D]; z=1: K -> [B,H,T,D]; z=2: V -> [B,H,D,T]
__global__ __launch_bounds__(256) void qkv_gemm(
    const _Float16* __restrict__ x16, const _Float16* __restrict__ wq,
    const _Float16* __restrict__ wk, const _Float16* __restrict__ wv,
    _Float16* __restrict__ qo, _Float16* __restrict__ ko, _Float16* __restrict__ vo) {
  const int tid = threadIdx.x;
  const int z = blockIdx.z;
  const _Float16* W = (z == 0) ? wq : (z == 1) ? wk : wv;
  const int m0 = blockIdx.y * 128, n0 = blockIdx.x * 128;
  const int wave = tid >> 6, lane = tid & 63;
  const int wr = wave >> 1, wc = wave & 1;
  const int lg = lane >> 4, lm = lane & 15;

  f32x4 acc[4][4];
  gemm_core(x16, W, m0, n0, tid, acc);

  if (z == 2) {
#pragma unroll
    for (int mt = 0; mt < 4; ++mt) {
      int mbase = m0 + wr * 64 + mt * 16 + lg * 4;  // row = m (b,t)
      int b = mbase >> 10, t = mbase & 1023;
#pragma unroll
      for (int nt = 0; nt < 4; ++nt) {
        int n = n0 + wc * 64 + nt * 16 + lm;  // col = n (h,d)
        int h = n >> 6, d = n & 63;
        half4 o;
#pragma unroll
        for (int r = 0; r < 4; ++r) o[r] = (_Float16)acc[mt][nt][r];
        *(half4*)&vo[(((size_t)(b * 16 + h) * 64 + d) << 10) + t] = o;
      }
    }
  } else {
    _Float16* dst = (z == 0) ? qo : ko;
    const float s = (z == 0) ? 0.125f : 1.0f;  // fold 1/sqrt(64) into Q
#pragma unroll
    for (int mt = 0; mt < 4; ++mt) {
      int mbase = m0 + wr * 64 + mt * 16 + lg * 4;
      int b = mbase >> 10, t = mbase & 1023;
#pragma unroll
      for (int nt = 0; nt < 4; ++nt) {
        int n = n0 + wc * 64 + nt * 16 + lm;
        int h = n >> 6, d = n & 63;
#pragma unroll
        for (int r = 0; r < 4; ++r)
          dst[((size_t)(b * 16 + h) * 1024 + t + r) * 64 + d] =
              (_Float16)(acc[mt][nt][r] * s);
      }
    }
  }
}

// ------------------------------------------------------------ attention -----
// grid (32 q-tiles, 64 bh), 512 threads = 8 waves (2 row-waves x 4 col-waves).
// Each wave: S strip 16 rows x 256 cols in registers (16 C-tiles). Full-row
// softmax via in-wave shuffles + LDS cross-wave combine. attn written once,
// nontemporal (never re-read; keeps K/V hot in L2 for sibling blocks).
// __launch_bounds__(512,4): cap at 128 VGPR -> 2 blocks/CU so the per-block
// 128 KB attn-store drain overlaps the co-resident block's compute.
__global__ __launch_bounds__(512, 4) void attn_fused(
    const _Float16* __restrict__ qg, const _Float16* __restrict__ kg,
    const _Float16* __restrict__ vg, float* __restrict__ attn,
    _Float16* __restrict__ y16) {
  const int bh = blockIdx.y;
  const int b = bh >> 4, h = bh & 15;
  const int q0 = blockIdx.x << 5;
  const int tid = threadIdx.x;
  const int wave = tid >> 6, lane = tid & 63;
  const int wr = wave >> 2, wc = wave & 3;
  const int lg = lane >> 4, lm = lane & 15;

  __shared__ _Float16 q_lds[32 * 72];        // pad 64->72 (2-way max, free)
  __shared__ _Float16 p_lds[8 * 16 * 40];    // per-wave 16x32 P, pad 32->40
  __shared__ float red[4][32];               // cross-wave softmax partials
  __shared__ float o_red[2][4][16 * 64];     // O partial reduction

  if (tid < 256) {
    int r = tid >> 3, c = tid & 7;
    *(half8*)&q_lds[r * 72 + c * 8] =
        *(const half8*)&qg[((size_t)bh * 1024 + q0 + r) * 64 + c * 8];
  }
  __syncthreads();

  f32x4 z4 = {0.f, 0.f, 0.f, 0.f};
  f32x4 acc[16];
#pragma unroll
  for (int i = 0; i < 16; ++i) acc[i] = z4;

  const int arow = wr * 16 + lm;
  half8 a0 = *(half8*)&q_lds[arow * 72 + lg * 8];
  half8 a1 = *(half8*)&q_lds[arow * 72 + 32 + lg * 8];
  const _Float16* kbase = kg + ((size_t)bh << 16);
#pragma unroll
  for (int nt = 0; nt < 16; ++nt) {
    int n = wc * 256 + nt * 16 + lm;
    half8 b0 = *(const half8*)&kbase[(size_t)n * 64 + lg * 8];
    half8 b1 = *(const half8*)&kbase[(size_t)n * 64 + 32 + lg * 8];
    acc[nt] = MFMA16(a0, b0, acc[nt]);
    acc[nt] = MFMA16(a1, b1, acc[nt]);
  }

  // ALiBi bias + row max (S layout: row=lg*4+r, col=lm per 16-tile)
  const float slope = exp2f(-0.5f * (float)(h + 1));
  const int qrow0 = q0 + wr * 16 + lg * 4;
  float mx[4] = {-1e30f, -1e30f, -1e30f, -1e30f};
#pragma unroll
  for (int nt = 0; nt < 16; ++nt) {
    int col = wc * 256 + nt * 16 + lm;
#pragma unroll
    for (int r = 0; r < 4; ++r) {
      float v = acc[nt][r] - slope * fabsf((float)(qrow0 + r - col));
      acc[nt][r] = v;
      mx[r] = fmaxf(mx[r], v);
    }
  }
#pragma unroll
  for (int r = 0; r < 4; ++r)
#pragma unroll
    for (int d = 1; d < 16; d <<= 1) mx[r] = fmaxf(mx[r], __shfl_xor(mx[r], d, 64));
  if (lm == 0) {
#pragma unroll
    for (int r = 0; r < 4; ++r) red[wc][wr * 16 + lg * 4 + r] = mx[r];
  }
  __syncthreads();
  float m[4];
#pragma unroll
  for (int r = 0; r < 4; ++r) {
    int row = wr * 16 + lg * 4 + r;
    m[r] = fmaxf(fmaxf(red[0][row], red[1][row]), fmaxf(red[2][row], red[3][row]));
  }
  __syncthreads();

  float sm[4] = {0.f, 0.f, 0.f, 0.f};
#pragma unroll
  for (int nt = 0; nt < 16; ++nt)
#pragma unroll
    for (int r = 0; r < 4; ++r) {
      float p = exp2f((acc[nt][r] - m[r]) * 1.4426950408889634f);
      acc[nt][r] = p;
      sm[r] += p;
    }
#pragma unroll
  for (int r = 0; r < 4; ++r)
#pragma unroll
    for (int d = 1; d < 16; d <<= 1) sm[r] += __shfl_xor(sm[r], d, 64);
  if (lm == 0) {
#pragma unroll
    for (int r = 0; r < 4; ++r) red[wc][wr * 16 + lg * 4 + r] = sm[r];
  }
  __syncthreads();
  float inv[4];
#pragma unroll
  for (int r = 0; r < 4; ++r) {
    int row = wr * 16 + lg * 4 + r;
    inv[r] = 1.0f / (red[0][row] + red[1][row] + red[2][row] + red[3][row]);
  }

  // normalize + write attn (fp32, write-once, nontemporal)
  float* abase = attn + ((size_t)bh << 20);
#pragma unroll
  for (int nt = 0; nt < 16; ++nt) {
    int col = wc * 256 + nt * 16 + lm;
#pragma unroll
    for (int r = 0; r < 4; ++r) {
      float pn = acc[nt][r] * inv[r];
      acc[nt][r] = pn;
      __builtin_nontemporal_store(pn, &abase[((size_t)(qrow0 + r) << 10) + col]);
    }
  }

  // PV: per 32-wide k-chunk, C-layout -> LDS -> A-layout, V^T gives 16B b-frags
  f32x4 oacc[4];
#pragma unroll
  for (int i = 0; i < 4; ++i) oacc[i] = z4;
  _Float16* pl = &p_lds[wave * 640];
  const _Float16* vbase = vg + ((size_t)bh << 16);
#pragma unroll
  for (int c = 0; c < 8; ++c) {
#pragma unroll
    for (int hv = 0; hv < 2; ++hv)
#pragma unroll
      for (int r = 0; r < 4; ++r)
        pl[(lg * 4 + r) * 40 + hv * 16 + lm] = (_Float16)acc[2 * c + hv][r];
    half8 pa = *(half8*)&pl[lm * 40 + lg * 8];
    int kk = wc * 256 + c * 32 + lg * 8;
#pragma unroll
    for (int dt = 0; dt < 4; ++dt) {
      half8 vb = *(const half8*)&vbase[(size_t)(dt * 16 + lm) * 1024 + kk];
      oacc[dt] = MFMA16(pa, vb, oacc[dt]);
    }
  }

  // cross-wave O reduction (4 col-waves per row-group)
#pragma unroll
  for (int dt = 0; dt < 4; ++dt)
#pragma unroll
    for (int r = 0; r < 4; ++r)
      o_red[wr][wc][(lg * 4 + r) * 64 + dt * 16 + lm] = oacc[dt][r];
  __syncthreads();
#pragma unroll
  for (int it = 0; it < 4; ++it) {
    int idx = tid + it * 512;  // 32 rows x 64 cols
    int row = idx >> 6, col = idx & 63;
    int r2 = row & 15, wrr = row >> 4;
    float s = o_red[wrr][0][r2 * 64 + col] + o_red[wrr][1][r2 * 64 + col] +
              o_red[wrr][2][r2 * 64 + col] + o_red[wrr][3][r2 * 64 + col];
    y16[((size_t)(b * 1024 + q0 + row)) * 1024 + h * 64 + col] = (_Float16)s;
  }
}

// ------------------------------------------------------------- out proj -----
__global__ __launch_bounds__(256) void proj_gemm(const _Float16* __restrict__ y16,
                                                 const _Float16* __restrict__ wp,
                                                 float* __restrict__ out) {
  const int tid = threadIdx.x;
  const int m0 = blockIdx.y * 128, n0 = blockIdx.x * 128;
  const int wave = tid >> 6, lane = tid & 63;
  const int wr = wave >> 1, wc = wave & 1;
  const int lg = lane >> 4, lm = lane & 15;

  f32x4 acc[4][4];
  gemm_core(y16, wp, m0, n0, tid, acc);

#pragma unroll
  for (int mt = 0; mt < 4; ++mt) {
    int mbase = m0 + wr * 64 + mt * 16 + lg * 4;
#pragma unroll
    for (int nt = 0; nt < 4; ++nt) {
      int n = n0 + wc * 64 + nt * 16 + lm;
#pragma unroll
      for (int r = 0; r < 4; ++r)
        __builtin_nontemporal_store(acc[mt][nt][r],
                                    &out[(size_t)(mbase + r) * 1024 + n]);
    }
  }
}

// --------------------------------------------------------------- launch -----
extern "C" void kernel_launch(void* const* d_in, const int* in_sizes, int n_in,
                              void* d_out, int out_size, void* d_ws, size_t ws_size,
                              hipStream_t stream) {
  const float* x = (const float*)d_in[0];
  const float* Wq = (const float*)d_in[1];
  const float* Wk = (const float*)d_in[2];
  const float* Wv = (const float*)d_in[3];
  const float* Wp = (const float*)d_in[4];
  float* out = (float*)d_out;

  char* ws = (char*)d_ws;
  _Float16* x16 = (_Float16*)(ws);                    // 8 MB
  _Float16* wq16 = (_Float16*)(ws + (8u << 20));      // 2 MB
  _Float16* wk16 = (_Float16*)(ws + (10u << 20));     // 2 MB
  _Float16* wv16 = (_Float16*)(ws + (12u << 20));     // 2 MB
  _Float16* wp16 = (_Float16*)(ws + (14u << 20));     // 2 MB
  _Float16* q16 = (_Float16*)(ws + (16u << 20));      // 8 MB  [B,H,T,D]
  _Float16* k16 = (_Float16*)(ws + (24u << 20));      // 8 MB  [B,H,T,D]
  _Float16* v16 = (_Float16*)(ws + (32u << 20));      // 8 MB  [B,H,D,T]
  _Float16* y16 = (_Float16*)(ws + (40u << 20));      // 8 MB  [B,T,C]

  cvt_all<<<8192, 256, 0, stream>>>(x, Wq, Wk, Wv, Wp, x16, wq16, wk16, wv16, wp16);

  qkv_gemm<<<dim3(8, 32, 3), 256, 0, stream>>>(x16, wq16, wk16, wv16, q16, k16, v16);
  attn_fused<<<dim3(32, 64), 512, 0, stream>>>(q16, k16, v16, out + 4194304, y16);
  proj_gemm<<<dim3(8, 32, 1), 256, 0, stream>>>(y16, wp16, out);
}